// Round 8
// baseline (1437.046 us; speedup 1.0000x reference)
//
#include <hip/hip_runtime.h>

#define B_   32
#define HW_  196
#define C_   512
#define M_   (B_*HW_)    // 6272
#define HID_ 128
#define NBLK 18
#define NBLOCKS 392      // persistent grid: 98 row-tiles x 4 col-tiles
#define NTHR    256

typedef _Float16 f16;
typedef _Float16 f16x8 __attribute__((ext_vector_type(8)));
typedef float    f32x4 __attribute__((ext_vector_type(4)));

__device__ __forceinline__ float gelu_f(float x) {
    float t = tanhf(0.7978845608028654f * (x + 0.044715f * x * x * x));
    return 0.5f * x * (1.0f + t);
}

// async global->LDS, 16B per lane; LDS dest = wave-uniform base + lane*16
__device__ __forceinline__ void gl16(const void* g, void* l) {
    __builtin_amdgcn_global_load_lds((const __attribute__((address_space(1))) unsigned*)g,
                                     (__attribute__((address_space(3))) unsigned*)l, 16, 0, 0);
}

// device-scope grid barrier: monotonic counter, no reset needed within a launch
__device__ __forceinline__ void grid_barrier(unsigned* cnt, unsigned target) {
    __syncthreads();
    if (threadIdx.x == 0) {
        __threadfence();                 // release this block's stores device-wide
        atomicAdd(cnt, 1u);              // device-scope by default on CDNA
        while (__hip_atomic_load(cnt, __ATOMIC_RELAXED, __HIP_MEMORY_SCOPE_AGENT) < target)
            __builtin_amdgcn_s_sleep(2);
        __threadfence();                 // acquire other blocks' stores
    }
    __syncthreads();
}

// ---------- weights: fp32 [blk][k][n] -> fp16 transposed [blk][n][k] ----------
__global__ __launch_bounds__(256) void conv_w(const float* __restrict__ W,
                                              f16* __restrict__ Wt) {
    __shared__ f16 sh[64][72];
    const int blk = blockIdx.z, k0 = blockIdx.x * 64, n0 = blockIdx.y * 64;
    const int tid = threadIdx.x;
    const float* Wb = W + (size_t)blk * C_ * C_;
    #pragma unroll
    for (int i = 0; i < 4; ++i) {
        int s = tid + i * 256, r = s >> 4, c4 = (s & 15) << 2;
        float4 v = *(const float4*)&Wb[(size_t)(k0 + r) * C_ + n0 + c4];
        sh[r][c4 + 0] = (f16)v.x; sh[r][c4 + 1] = (f16)v.y;
        sh[r][c4 + 2] = (f16)v.z; sh[r][c4 + 3] = (f16)v.w;
    }
    __syncthreads();
    #pragma unroll
    for (int i = 0; i < 2; ++i) {
        int s = tid + i * 256, r = s >> 3, c8 = (s & 7) << 3;
        f16x8 o;
        #pragma unroll
        for (int j = 0; j < 8; ++j) o[j] = sh[c8 + j][r];
        *(f16x8*)&Wt[(size_t)blk * C_ * C_ + (size_t)(n0 + r) * C_ + k0 + c8] = o;
    }
}

// ---------- x: fp32 -> fp16 ----------
__global__ __launch_bounds__(256) void conv_x(const float* __restrict__ in,
                                              f16* __restrict__ out) {
    int i = blockIdx.x * 256 + threadIdx.x;
    out[i] = (f16)in[i];
}

// ---------- persistent kernel: all 18 layers + gating, grid-barrier synced ----------
// Block tile 64x128 (row0=(blk>>2)*64, col0=(blk&3)*128), 4 waves of 32x64
// (2x4 16x16x32 frags). LDS: As 2x8KB dbuf + Ws 2x16KB dbuf + gate scratch.
__global__ __launch_bounds__(256, 2) void stage_persistent(
    f16* __restrict__ P0, f16* __restrict__ P1, f16* __restrict__ A0,
    f16* __restrict__ A1, f16* __restrict__ A2,
    const f16* __restrict__ Wt, const float* __restrict__ ball,
    const float* __restrict__ fc1w, const float* __restrict__ fc1b,
    const float* __restrict__ fc2w, const float* __restrict__ fc2b,
    const float* __restrict__ gammas,
    float* __restrict__ pooled, float* __restrict__ gates,
    unsigned* __restrict__ cnt, float* __restrict__ out)
{
    // buffer schedule (ids into bufs[]): verified r3-r6
    const int insid[NBLK]  = {1,0,2,0,1,3,0,1,0,1,4,0,1,0,1,0,1,0};
    const int outsid[NBLK] = {0,2,0,1,3,0,1,0,1,4,0,1,0,1,0,1,0,1};
    f16* bufs[5] = {P0, P1, A0, A1, A2};

    const int tid = threadIdx.x, blk = blockIdx.x;
    const int wave = tid >> 6, lane = tid & 63;
    const int m15 = lane & 15, q = lane >> 4;
    const int wr = wave >> 1, wc = wave & 1;          // 2x2 wave grid -> 32x64 tiles
    const int row0 = (blk >> 2) * 64, col0 = (blk & 3) * 128;
    const int srow = lane >> 3;
    const int scol = ((lane & 7) ^ (srow & 7)) << 3;  // XOR-16B swizzle (halfs)

    __shared__ f16 AsB[2][64 * 64];     // 2 x 8 KB
    __shared__ f16 WsB[2][128 * 64];    // 2 x 16 KB
    __shared__ float spG[C_];           // gate scratch (separate; +2.5 KB)
    __shared__ float shG[HID_];

    unsigned bar = 0;

    for (int L = 0; L < NBLK; ++L) {
        const f16* Ain  = bufs[insid[L]];
        f16*       Aout = bufs[outsid[L]];
        const f16* Wb   = Wt + (size_t)L * C_ * C_;
        const float* bias = ball + (size_t)L * C_;

        // ---- GEMM: Aout[row0:+64, col0:+128] = gelu(Ain @ W + b) ----
        const f16* aSrc[2]; const f16* wSrc[4]; int aOff[2], wOff[4];
        #pragma unroll
        for (int i = 0; i < 2; ++i) {
            int ch = wave * 2 + i;
            aSrc[i] = Ain + (size_t)(row0 + ch * 8 + srow) * C_ + scol;
            aOff[i] = ch * 512;
        }
        #pragma unroll
        for (int i = 0; i < 4; ++i) {
            int ch = wave * 4 + i;
            wSrc[i] = Wb + (size_t)(col0 + ch * 8 + srow) * C_ + scol;
            wOff[i] = ch * 512;
        }

        f32x4 acc[2][4];
        #pragma unroll
        for (int i = 0; i < 2; ++i)
            #pragma unroll
            for (int j = 0; j < 4; ++j) acc[i][j] = (f32x4)0.f;

        // prefetch tile 0 -> buf 0 (LDS safe: barrier synced before reuse)
        #pragma unroll
        for (int i = 0; i < 2; ++i) gl16(aSrc[i], &AsB[0][aOff[i]]);
        #pragma unroll
        for (int i = 0; i < 4; ++i) gl16(wSrc[i], &WsB[0][wOff[i]]);

        for (int kt = 0; kt < C_ / 64; ++kt) {
            __syncthreads();     // drains this tile's loads + buffer reuse
            int cur = kt & 1;
            if (kt + 1 < C_ / 64) {
                int nxt = cur ^ 1, koff = (kt + 1) * 64;
                #pragma unroll
                for (int i = 0; i < 2; ++i) gl16(aSrc[i] + koff, &AsB[nxt][aOff[i]]);
                #pragma unroll
                for (int i = 0; i < 4; ++i) gl16(wSrc[i] + koff, &WsB[nxt][wOff[i]]);
            }
            #pragma unroll
            for (int kk = 0; kk < 64; kk += 32) {
                f16x8 af[2], bf[4];
                #pragma unroll
                for (int i = 0; i < 2; ++i) {
                    int r = wr * 32 + i * 16 + m15;
                    int c = (kk >> 3) + q;
                    af[i] = *(const f16x8*)&AsB[cur][r * 64 + ((c ^ (r & 7)) << 3)];
                }
                #pragma unroll
                for (int j = 0; j < 4; ++j) {
                    int r = wc * 64 + j * 16 + m15;
                    int c = (kk >> 3) + q;
                    bf[j] = *(const f16x8*)&WsB[cur][r * 64 + ((c ^ (r & 7)) << 3)];
                }
                #pragma unroll
                for (int i = 0; i < 2; ++i)
                    #pragma unroll
                    for (int j = 0; j < 4; ++j)
                        acc[i][j] = __builtin_amdgcn_mfma_f32_16x16x32_f16(af[i], bf[j], acc[i][j], 0, 0, 0);
            }
        }

        // epilogue: C/D layout col=lane&15, row=quad*4+reg
        float bcol[4];
        #pragma unroll
        for (int j = 0; j < 4; ++j) bcol[j] = bias[col0 + wc * 64 + j * 16 + m15];
        #pragma unroll
        for (int i = 0; i < 2; ++i)
            #pragma unroll
            for (int r = 0; r < 4; ++r) {
                int row = row0 + wr * 32 + i * 16 + q * 4 + r;
                #pragma unroll
                for (int j = 0; j < 4; ++j) {
                    int col = col0 + wc * 64 + j * 16 + m15;
                    Aout[(size_t)row * C_ + col] = (f16)gelu_f(acc[i][j][r] + bcol[j]);
                }
            }

        grid_barrier(cnt, (++bar) * NBLOCKS);

        int t = (L == 11) ? 0 : (L == 14) ? 1 : (L == 17) ? 2 : -1;
        if (t >= 0) {
            // ---- pool: mean over 196 spatial rows -> pooled[32][512] ----
            if (blk < 64) {
                int b = blk >> 1, c = ((blk & 1) << 8) + tid;
                const f16* p = Aout + (size_t)b * HW_ * C_ + c;
                float s = 0.f;
                #pragma unroll 4
                for (int i = 0; i < HW_; ++i) s += (float)p[(size_t)i * C_];
                pooled[b * C_ + c] = s * (1.f / 196.f);
            }
            grid_barrier(cnt, (++bar) * NBLOCKS);

            // ---- gate: 2-layer MLP + softmax over anchors; blocks 0..31 ----
            if (blk < 32) {
                int b = blk;
                spG[tid]       = pooled[b * C_ + tid];
                spG[tid + 256] = pooled[b * C_ + tid + 256];
                __syncthreads();
                if (tid < HID_) {
                    const float* w = fc1w + (size_t)t * C_ * HID_ + tid;
                    float s = fc1b[t * HID_ + tid];
                    for (int c = 0; c < C_; ++c) s += spG[c] * w[(size_t)c * HID_];
                    shG[tid] = gelu_f(s);
                }
                __syncthreads();
                #pragma unroll
                for (int cc = 0; cc < 2; ++cc) {
                    int c = tid + cc * 256;
                    const float* w2 = fc2w + (size_t)t * HID_ * (3 * C_) + c;
                    float l0 = fc2b[t * 3 * C_ + c];
                    float l1 = fc2b[t * 3 * C_ + C_ + c];
                    float l2 = fc2b[t * 3 * C_ + 2 * C_ + c];
                    for (int j = 0; j < HID_; ++j) {
                        float h = shG[j];
                        const float* r = w2 + (size_t)j * 3 * C_;
                        l0 += h * r[0];
                        l1 += h * r[C_];
                        l2 += h * r[2 * C_];
                    }
                    float m  = fmaxf(l0, fmaxf(l1, l2));
                    float e0 = expf(l0 - m), e1 = expf(l1 - m), e2 = expf(l2 - m);
                    float inv = 1.f / (e0 + e1 + e2);
                    gates[(size_t)b * 3 * C_ + c]          = e0 * inv;
                    gates[(size_t)b * 3 * C_ + C_ + c]     = e1 * inv;
                    gates[(size_t)b * 3 * C_ + 2 * C_ + c] = e2 * inv;
                }
            }
            grid_barrier(cnt, (++bar) * NBLOCKS);

            // ---- routed add: nx += gamma * sum_a g[b,a,c]*anchor_a ----
            {
                float gamma = gammas[t];
                // NB/8 = 401408 chunks; 392*256 = 100352 threads -> exactly 4 each
                for (int chunk = blk * NTHR + tid; chunk < M_ * C_ / 8; chunk += NBLOCKS * NTHR) {
                    size_t base = (size_t)chunk * 8;
                    int c8 = (int)(base & (C_ - 1));
                    int b  = chunk / (HW_ * C_ / 8);
                    const float* g = gates + (size_t)b * 3 * C_;
                    f16x8 xv = *(const f16x8*)&Aout[base];
                    f16x8 v0 = *(const f16x8*)&A0[base];
                    f16x8 v1 = *(const f16x8*)&A1[base];
                    f16x8 v2 = *(const f16x8*)&A2[base];
                    float r[8];
                    #pragma unroll
                    for (int e = 0; e < 8; ++e) {
                        r[e] = (float)xv[e] + gamma * (g[c8 + e] * (float)v0[e]
                              + g[C_ + c8 + e] * (float)v1[e]
                              + g[2 * C_ + c8 + e] * (float)v2[e]);
                    }
                    if (t == 2) {
                        float4 o0 = make_float4(r[0], r[1], r[2], r[3]);
                        float4 o1 = make_float4(r[4], r[5], r[6], r[7]);
                        *(float4*)&out[base]     = o0;
                        *(float4*)&out[base + 4] = o1;
                    } else {
                        f16x8 o;
                        #pragma unroll
                        for (int e = 0; e < 8; ++e) o[e] = (f16)r[e];
                        *(f16x8*)&Aout[base] = o;
                    }
                }
            }
            if (L < NBLK - 1) grid_barrier(cnt, (++bar) * NBLOCKS);
        }
    }
}

extern "C" void kernel_launch(void* const* d_in, const int* in_sizes, int n_in,
                              void* d_out, int out_size, void* d_ws, size_t ws_size,
                              hipStream_t stream)
{
    const float* x      = (const float*)d_in[0];
    const float* blockw = (const float*)d_in[1];
    const float* blockb = (const float*)d_in[2];
    const float* fc1w   = (const float*)d_in[3];
    const float* fc1b   = (const float*)d_in[4];
    const float* fc2w   = (const float*)d_in[5];
    const float* fc2b   = (const float*)d_in[6];
    const float* gammas = (const float*)d_in[7];
    float* out = (float*)d_out;

    const size_t NB = (size_t)M_ * C_;            // 3,211,264 elems/activation
    f16* Wt = (f16*)d_ws;                          // 18*512*512 halfs = 9.44MB
    f16* P0 = Wt + (size_t)NBLK * C_ * C_;
    f16* P1 = P0 + NB;
    f16* A0 = P0 + 2 * NB;
    f16* A1 = P0 + 3 * NB;
    f16* A2 = P0 + 4 * NB;
    float* pooled = (float*)(P0 + 5 * NB);
    float* gates  = pooled + B_ * C_;
    unsigned* cnt = (unsigned*)(gates + B_ * 3 * C_);

    (void)hipMemsetAsync(cnt, 0, 64, stream);     // zero the barrier counter
    conv_w<<<dim3(8, 8, NBLK), 256, 0, stream>>>(blockw, Wt);
    conv_x<<<(int)(NB / 256), 256, 0, stream>>>(x, P1);

    stage_persistent<<<NBLOCKS, NTHR, 0, stream>>>(
        P0, P1, A0, A1, A2, Wt, blockb,
        fc1w, fc1b, fc2w, fc2b, gammas,
        pooled, gates, cnt, out);
}

// Round 9
// 687.543 us; speedup vs baseline: 2.0901x; 2.0901x over previous
//
#include <hip/hip_runtime.h>

#define B_   32
#define HW_  196
#define C_   512
#define M_   (B_*HW_)    // 6272
#define HID_ 128
#define NBLK 18
#define NGRID 196        // one block per 32-row stripe
#define NTHR  512        // 8 waves; each wave owns 64 output cols
#define LDP   520        // padded LDS row stride (halfs): 1040 B

typedef _Float16 f16;
typedef _Float16 f16x8 __attribute__((ext_vector_type(8)));
typedef float    f32x4 __attribute__((ext_vector_type(4)));

__device__ __forceinline__ float gelu_f(float x) {
    float t = tanhf(0.7978845608028654f * (x + 0.044715f * x * x * x));
    return 0.5f * x * (1.0f + t);
}

// arrival-counter + release-flag grid barrier (counter and flag on separate
// lines; pollers only touch the flag, at ~2048-cycle intervals)
__device__ __forceinline__ void grid_barrier(unsigned* cnt, unsigned* rel, unsigned epoch) {
    __syncthreads();
    if (threadIdx.x == 0) {
        __threadfence();                                  // release our stores
        unsigned old = atomicAdd(cnt, 1u);
        if (old == epoch * NGRID - 1) {
            __hip_atomic_store(rel, epoch, __ATOMIC_RELEASE, __HIP_MEMORY_SCOPE_AGENT);
        } else {
            while (__hip_atomic_load(rel, __ATOMIC_ACQUIRE, __HIP_MEMORY_SCOPE_AGENT) < epoch)
                __builtin_amdgcn_s_sleep(32);
        }
        __threadfence();                                  // acquire: inv local caches
    }
    __syncthreads();
}

// ---------- weights: fp32 [blk][k][n] -> fp16 transposed [blk][n][k] ----------
__global__ __launch_bounds__(256) void conv_w(const float* __restrict__ W,
                                              f16* __restrict__ Wt) {
    __shared__ f16 sh[64][72];
    const int blk = blockIdx.z, k0 = blockIdx.x * 64, n0 = blockIdx.y * 64;
    const int tid = threadIdx.x;
    const float* Wb = W + (size_t)blk * C_ * C_;
    #pragma unroll
    for (int i = 0; i < 4; ++i) {
        int s = tid + i * 256, r = s >> 4, c4 = (s & 15) << 2;
        float4 v = *(const float4*)&Wb[(size_t)(k0 + r) * C_ + n0 + c4];
        sh[r][c4 + 0] = (f16)v.x; sh[r][c4 + 1] = (f16)v.y;
        sh[r][c4 + 2] = (f16)v.z; sh[r][c4 + 3] = (f16)v.w;
    }
    __syncthreads();
    #pragma unroll
    for (int i = 0; i < 2; ++i) {
        int s = tid + i * 256, r = s >> 3, c8 = (s & 7) << 3;
        f16x8 o;
        #pragma unroll
        for (int j = 0; j < 8; ++j) o[j] = sh[c8 + j][r];
        *(f16x8*)&Wt[(size_t)blk * C_ * C_ + (size_t)(n0 + r) * C_ + k0 + c8] = o;
    }
}

// ---------- persistent: 18 layers, activations resident in LDS ----------
// Block owns rows [blk*32, blk*32+32). 8 waves x 64 cols; per wave 2x4 frags
// of 16x16x32. W read as register B-frags from L2, double-buffered per k-step.
__global__ __launch_bounds__(NTHR, 2) void stage_persistent(
    const float* __restrict__ x, const f16* __restrict__ Wt,
    const float* __restrict__ ball,
    const float* __restrict__ fc1w, const float* __restrict__ fc1b,
    const float* __restrict__ fc2w, const float* __restrict__ fc2b,
    const float* __restrict__ gammas,
    f16* __restrict__ Anc0, f16* __restrict__ Anc1, f16* __restrict__ Anc2,
    float* __restrict__ pooled, float* __restrict__ gates,
    unsigned* __restrict__ cnt, unsigned* __restrict__ rel,
    float* __restrict__ out)
{
    __shared__ f16 act[2][32][LDP];     // 66,560 B ping-pong activation stripe
    __shared__ float spG[C_];
    __shared__ float shG[HID_];

    const int tid = threadIdx.x, blk = blockIdx.x;
    const int lane = tid & 63, wave = tid >> 6;
    const int m15 = lane & 15, q = lane >> 4;
    const int row0 = blk * 32;
    const int ncol0 = wave * 64;

    // layer-0 input: x fp32 rows -> act[0] fp16
    for (int ch = tid; ch < 32 * 128; ch += NTHR) {
        int r = ch >> 7, c4 = (ch & 127) << 2;
        float4 v = *(const float4*)&x[(size_t)(row0 + r) * C_ + c4];
        act[0][r][c4 + 0] = (f16)v.x; act[0][r][c4 + 1] = (f16)v.y;
        act[0][r][c4 + 2] = (f16)v.z; act[0][r][c4 + 3] = (f16)v.w;
    }
    __syncthreads();

    unsigned epoch = 0;

    for (int L = 0; L < NBLK; ++L) {
        const int cur = L & 1, nxt = cur ^ 1;
        const f16* WL = Wt + (size_t)L * C_ * C_;
        const float* bias = ball + (size_t)L * C_;

        f32x4 acc[2][4];
        #pragma unroll
        for (int i = 0; i < 2; ++i)
            #pragma unroll
            for (int j = 0; j < 4; ++j) acc[i][j] = (f32x4)0.f;

        const f16* wp[4];
        #pragma unroll
        for (int j = 0; j < 4; ++j)
            wp[j] = WL + (size_t)(ncol0 + j * 16 + m15) * C_ + q * 8;

        f16x8 bfr[2][4];
        #pragma unroll
        for (int j = 0; j < 4; ++j) bfr[0][j] = *(const f16x8*)wp[j];

        #pragma unroll
        for (int kt = 0; kt < 16; ++kt) {
            const int pb = kt & 1;
            if (kt < 15) {
                #pragma unroll
                for (int j = 0; j < 4; ++j)
                    bfr[pb ^ 1][j] = *(const f16x8*)(wp[j] + (kt + 1) * 32);
            }
            f16x8 af[2];
            #pragma unroll
            for (int i = 0; i < 2; ++i)
                af[i] = *(const f16x8*)&act[cur][i * 16 + m15][kt * 32 + q * 8];
            #pragma unroll
            for (int i = 0; i < 2; ++i)
                #pragma unroll
                for (int j = 0; j < 4; ++j)
                    acc[i][j] = __builtin_amdgcn_mfma_f32_16x16x32_f16(af[i], bfr[pb][j], acc[i][j], 0, 0, 0);
        }

        // epilogue (C/D layout col=lane&15, row=quad*4+reg): gelu -> act[nxt]
        float bcol[4];
        #pragma unroll
        for (int j = 0; j < 4; ++j) bcol[j] = bias[ncol0 + j * 16 + m15];
        #pragma unroll
        for (int i = 0; i < 2; ++i)
            #pragma unroll
            for (int r = 0; r < 4; ++r) {
                int row = i * 16 + q * 4 + r;
                #pragma unroll
                for (int j = 0; j < 4; ++j)
                    act[nxt][row][ncol0 + j * 16 + m15] = (f16)gelu_f(acc[i][j][r] + bcol[j]);
            }
        __syncthreads();

        // anchor layers: spill stripe to global (row-local; same block reads back)
        int ai = (L == 1) ? 0 : (L == 4) ? 1 : (L == 9) ? 2 : -1;
        if (ai >= 0) {
            f16* dst = (ai == 0 ? Anc0 : ai == 1 ? Anc1 : Anc2) + (size_t)row0 * C_;
            for (int ch = tid; ch < 32 * 64; ch += NTHR) {
                int r = ch >> 6, c8 = (ch & 63) << 3;
                *(f16x8*)&dst[(size_t)r * C_ + c8] = *(const f16x8*)&act[nxt][r][c8];
            }
        }

        int t = (L == 11) ? 0 : (L == 14) ? 1 : (L == 17) ? 2 : -1;
        if (t >= 0) {
            // pool partials: this stripe spans <=2 batches
            {
                int c = tid;                         // NTHR == C_
                int b0 = row0 / HW_;
                int rs = (b0 + 1) * HW_ - row0; if (rs > 32) rs = 32;
                float s0 = 0.f, s1 = 0.f;
                for (int r = 0; r < rs; ++r)  s0 += (float)act[nxt][r][c];
                for (int r = rs; r < 32; ++r) s1 += (float)act[nxt][r][c];
                atomicAdd(&pooled[(size_t)(t * B_ + b0) * C_ + c], s0);
                if (rs < 32) atomicAdd(&pooled[(size_t)(t * B_ + b0 + 1) * C_ + c], s1);
            }
            grid_barrier(cnt, rel, ++epoch);

            // gate MLP + softmax: blocks 0..31, one batch each
            if (blk < B_) {
                int b = blk;
                spG[tid] = pooled[(size_t)(t * B_ + b) * C_ + tid] * (1.f / 196.f);
                __syncthreads();
                if (tid < HID_) {
                    const float* w = fc1w + (size_t)t * C_ * HID_ + tid;
                    float s = fc1b[t * HID_ + tid];
                    for (int c = 0; c < C_; ++c) s += spG[c] * w[(size_t)c * HID_];
                    shG[tid] = gelu_f(s);
                }
                __syncthreads();
                {
                    int c = tid;
                    const float* w2 = fc2w + (size_t)t * HID_ * (3 * C_) + c;
                    float l0 = fc2b[t * 3 * C_ + c];
                    float l1 = fc2b[t * 3 * C_ + C_ + c];
                    float l2 = fc2b[t * 3 * C_ + 2 * C_ + c];
                    for (int j = 0; j < HID_; ++j) {
                        float h = shG[j];
                        const float* rw = w2 + (size_t)j * 3 * C_;
                        l0 += h * rw[0]; l1 += h * rw[C_]; l2 += h * rw[2 * C_];
                    }
                    float m = fmaxf(l0, fmaxf(l1, l2));
                    float e0 = expf(l0 - m), e1 = expf(l1 - m), e2 = expf(l2 - m);
                    float inv = 1.f / (e0 + e1 + e2);
                    gates[(size_t)b * 3 * C_ + c]          = e0 * inv;
                    gates[(size_t)b * 3 * C_ + C_ + c]     = e1 * inv;
                    gates[(size_t)b * 3 * C_ + 2 * C_ + c] = e2 * inv;
                }
            }
            grid_barrier(cnt, rel, ++epoch);

            // routed add (row-local): act[nxt] += gamma * sum_a g[b,a,c]*anchor
            {
                float gamma = gammas[t];
                const f16* a0 = Anc0 + (size_t)row0 * C_;
                const f16* a1 = Anc1 + (size_t)row0 * C_;
                const f16* a2 = Anc2 + (size_t)row0 * C_;
                for (int ch = tid; ch < 32 * 64; ch += NTHR) {
                    int r = ch >> 6, c8 = (ch & 63) << 3;
                    int b = (row0 + r) / HW_;
                    const float* g = gates + (size_t)b * 3 * C_ + c8;
                    f16x8 xv = *(const f16x8*)&act[nxt][r][c8];
                    f16x8 v0 = *(const f16x8*)&a0[(size_t)r * C_ + c8];
                    f16x8 v1 = *(const f16x8*)&a1[(size_t)r * C_ + c8];
                    f16x8 v2 = *(const f16x8*)&a2[(size_t)r * C_ + c8];
                    float rr[8];
                    #pragma unroll
                    for (int e = 0; e < 8; ++e)
                        rr[e] = (float)xv[e] + gamma * (g[e] * (float)v0[e]
                              + g[C_ + e] * (float)v1[e] + g[2 * C_ + e] * (float)v2[e]);
                    if (t == 2) {
                        size_t o = (size_t)(row0 + r) * C_ + c8;
                        *(float4*)&out[o]     = make_float4(rr[0], rr[1], rr[2], rr[3]);
                        *(float4*)&out[o + 4] = make_float4(rr[4], rr[5], rr[6], rr[7]);
                    } else {
                        f16x8 o8;
                        #pragma unroll
                        for (int e = 0; e < 8; ++e) o8[e] = (f16)rr[e];
                        *(f16x8*)&act[nxt][r][c8] = o8;
                    }
                }
            }
            __syncthreads();
        }
    }
}

extern "C" void kernel_launch(void* const* d_in, const int* in_sizes, int n_in,
                              void* d_out, int out_size, void* d_ws, size_t ws_size,
                              hipStream_t stream)
{
    const float* x      = (const float*)d_in[0];
    const float* blockw = (const float*)d_in[1];
    const float* blockb = (const float*)d_in[2];
    const float* fc1w   = (const float*)d_in[3];
    const float* fc1b   = (const float*)d_in[4];
    const float* fc2w   = (const float*)d_in[5];
    const float* fc2b   = (const float*)d_in[6];
    const float* gammas = (const float*)d_in[7];
    float* out = (float*)d_out;

    const size_t NB = (size_t)M_ * C_;            // 3,211,264 elems
    f16* Wt   = (f16*)d_ws;                        // 9.44 MB
    f16* Anc0 = Wt + (size_t)NBLK * C_ * C_;       // 6.42 MB each
    f16* Anc1 = Anc0 + NB;
    f16* Anc2 = Anc1 + NB;
    float* pooled = (float*)(Anc2 + NB);           // [3][32][512]
    float* gates  = pooled + 3 * B_ * C_;          // [32][3][512]
    unsigned* cnt = (unsigned*)(gates + B_ * 3 * C_);
    unsigned* rel = cnt + 32;                      // separate cache line

    // zero pooled + gates + barrier words (one contiguous region)
    (void)hipMemsetAsync(pooled, 0, (size_t)(3 * B_ * C_ + B_ * 3 * C_) * 4 + 256, stream);
    conv_w<<<dim3(8, 8, NBLK), 256, 0, stream>>>(blockw, Wt);

    stage_persistent<<<NGRID, NTHR, 0, stream>>>(
        x, Wt, blockb, fc1w, fc1b, fc2w, fc2b, gammas,
        Anc0, Anc1, Anc2, pooled, gates, cnt, rel, out);
}